// Round 1
// 73.966 us; speedup vs baseline: 1.0165x; 1.0165x over previous
//
#include <hip/hip_runtime.h>

#define NB 16
#define N_IN 512
#define N_OUT 4096
#define OUT_CH 64
#define M_TILE 64                // 1 m per thread -> 1024 blocks, 4 waves/SIMD
#define NCHUNK 4                 // 4 waves split the n loop
#define NPER (N_IN / NCHUNK)     // 128 n per thread
#define NQUAD (NPER / 4)         // 32 float4 quads per thread

__global__ __launch_bounds__(256, 4) void convdeepset_kernel(
    const float* __restrict__ x,
    const float* __restrict__ y,
    const float* __restrict__ t,
    const float* __restrict__ sigma,
    const float* __restrict__ W,
    const float* __restrict__ bias,
    float* __restrict__ out)
{
    __shared__ float sp[N_IN];           // p = k*x^2   (slow path: x)
    __shared__ float sq[N_IN];           // q = -2k*x   (slow path: unused)
    __shared__ float sy[N_IN];           // y
    __shared__ float red0[256];
    __shared__ float red1[256];
    __shared__ float f0[M_TILE];
    __shared__ float f1[M_TILE];
    __shared__ float wf[OUT_CH * 2];
    __shared__ float bf[OUT_CH];

    const int tid = threadIdx.x;
    const int blk = blockIdx.x;          // b * (N_OUT/M_TILE) + mtile
    const int b   = blk >> 6;            // N_OUT/M_TILE == 64
    const int mt  = blk & 63;
    const int m0  = mt * M_TILE;

    // k_c = -0.5/exp(sigma_c)^2 * log2(e)  (exp2-ready)
    const float LOG2E = 1.4426950408889634f;
    const float s0 = sigma[0];
    const float s1 = sigma[1];
    const float k0 = -0.5f * __builtin_amdgcn_exp2f(-2.0f * s0 * LOG2E) * LOG2E;
    const float k1 = -0.5f * __builtin_amdgcn_exp2f(-2.0f * s1 * LOG2E) * LOG2E;
    const bool fast = (k0 == k1);

    // stage per-n terms into LDS (SoA: hot loop reads 3 b128 per 4 n)
    for (int i = tid; i < N_IN; i += 256) {
        float xv = x[b * N_IN + i];
        float yv = y[b * N_IN + i];
        if (fast) {
            sp[i] = k0 * xv * xv;        // p
            sq[i] = -2.0f * k0 * xv;     // q
        } else {
            sp[i] = xv;                  // raw x for slow path
            sq[i] = 0.0f;
        }
        sy[i] = yv;
    }
    if (tid < OUT_CH * 2) wf[tid] = W[tid];
    if (tid < OUT_CH)     bf[tid] = bias[tid];
    __syncthreads();

    const int l  = tid & 63;             // lane-in-wave = m offset
    const int nc = tid >> 6;             // wave id = n chunk
    const int qbase = nc * NQUAD;        // float4-quad base

    const float tv = t[b * N_OUT + m0 + l];

    // dual accumulator chains: serial dep depth 128 -> 64
    float a0 = 0.0f, a1 = 0.0f;          // dens / conv (even slots)
    float a0b = 0.0f, a1b = 0.0f;        // dens / conv (odd slots)

    const float4* sp4 = reinterpret_cast<const float4*>(sp);
    const float4* sq4 = reinterpret_cast<const float4*>(sq);
    const float4* sy4 = reinterpret_cast<const float4*>(sy);

    if (fast) {
        // exp2(k(x-t)^2) = exp2(fma(q,t,p)) * exp2(k t^2); fold the latter out.
        // max exponent of fma(q,t,p) is ~72 for x,t in [0,1], k=-72 -> no overflow.
        #pragma unroll 4
        for (int qi = 0; qi < NQUAD; ++qi) {
            float4 p4 = sp4[qbase + qi];
            float4 q4 = sq4[qbase + qi];
            float4 y4 = sy4[qbase + qi];
            float e0 = __builtin_amdgcn_exp2f(fmaf(q4.x, tv, p4.x));
            float e1 = __builtin_amdgcn_exp2f(fmaf(q4.y, tv, p4.y));
            float e2 = __builtin_amdgcn_exp2f(fmaf(q4.z, tv, p4.z));
            float e3 = __builtin_amdgcn_exp2f(fmaf(q4.w, tv, p4.w));
            a0  += e0; a1  = fmaf(y4.x, e0, a1);
            a0b += e1; a1b = fmaf(y4.y, e1, a1b);
            a0  += e2; a1  = fmaf(y4.z, e2, a1);
            a0b += e3; a1b = fmaf(y4.w, e3, a1b);
        }
        const float et = __builtin_amdgcn_exp2f(k0 * tv * tv);
        a0 = (a0 + a0b) * et;
        a1 = (a1 + a1b) * et;
    } else {
        #pragma unroll 4
        for (int qi = 0; qi < NQUAD; ++qi) {
            float4 x4 = sp4[qbase + qi];
            float4 y4 = sy4[qbase + qi];
            float xv[4] = {x4.x, x4.y, x4.z, x4.w};
            float yv[4] = {y4.x, y4.y, y4.z, y4.w};
            #pragma unroll
            for (int j = 0; j < 4; ++j) {
                float dx = xv[j] - tv;
                float d2 = dx * dx;
                float e0 = __builtin_amdgcn_exp2f(k0 * d2);
                float e1 = __builtin_amdgcn_exp2f(k1 * d2);
                if (j & 1) { a0b += e0; a1b = fmaf(yv[j], e1, a1b); }
                else       { a0  += e0; a1  = fmaf(yv[j], e1, a1); }
            }
        }
        a0 += a0b;
        a1 += a1b;
    }

    red0[tid] = a0;
    red1[tid] = a1;
    __syncthreads();

    if (tid < M_TILE) {
        float dens = red0[tid] + red0[tid + 64] + red0[tid + 128] + red0[tid + 192];
        float conv = red1[tid] + red1[tid + 64] + red1[tid + 128] + red1[tid + 192];
        f0[tid] = dens;
        f1[tid] = conv / (dens + 1e-8f);
    }
    __syncthreads();

    // epilogue: out[b, m, o] = W[o,0]*dens + W[o,1]*normalized + b[o]
    const size_t obase = (size_t)(b * N_OUT + m0) * OUT_CH;
    for (int p = tid; p < M_TILE * OUT_CH / 4; p += 256) {
        int mloc = p >> 4;               // 16 float4s per m
        int o    = (p & 15) * 4;
        float d = f0[mloc], nrm = f1[mloc];
        float4 v;
        v.x = fmaf(wf[2 * (o + 0) + 0], d, fmaf(wf[2 * (o + 0) + 1], nrm, bf[o + 0]));
        v.y = fmaf(wf[2 * (o + 1) + 0], d, fmaf(wf[2 * (o + 1) + 1], nrm, bf[o + 1]));
        v.z = fmaf(wf[2 * (o + 2) + 0], d, fmaf(wf[2 * (o + 2) + 1], nrm, bf[o + 2]));
        v.w = fmaf(wf[2 * (o + 3) + 0], d, fmaf(wf[2 * (o + 3) + 1], nrm, bf[o + 3]));
        *reinterpret_cast<float4*>(out + obase + (size_t)mloc * OUT_CH + o) = v;
    }
}

extern "C" void kernel_launch(void* const* d_in, const int* in_sizes, int n_in,
                              void* d_out, int out_size, void* d_ws, size_t ws_size,
                              hipStream_t stream) {
    const float* x     = (const float*)d_in[0];
    const float* y     = (const float*)d_in[1];
    const float* t     = (const float*)d_in[2];
    const float* sigma = (const float*)d_in[3];
    const float* W     = (const float*)d_in[4];
    const float* bias  = (const float*)d_in[5];
    float* out = (float*)d_out;

    dim3 grid(NB * (N_OUT / M_TILE));    // 16 * 64 = 1024 blocks
    convdeepset_kernel<<<grid, 256, 0, stream>>>(x, y, t, sigma, W, bias, out);
}